// Round 1
// baseline (1537.854 us; speedup 1.0000x reference)
//
#include <hip/hip_runtime.h>
#include <hip/hip_bf16.h>
#include <math.h>

#define B_  4
#define S_  2048
#define D_  512
#define H_  8
#define DK_ 64
#define BS_ (B_*S_)

// ---------------------------------------------------------------------------
// GEMM: C[M,512] = A[M,512] @ W[512,512] + bias   (f32, 64x64 tile, BK=16)
// ---------------------------------------------------------------------------
__global__ __launch_bounds__(256) void gemm_bias_kernel(
    const float* __restrict__ A, const float* __restrict__ W,
    const float* __restrict__ bias, float* __restrict__ C) {
  constexpr int K = D_, N = D_;
  __shared__ float As[16][72];   // [k][m], row stride 288B (16B-aligned)
  __shared__ float Ws[16][72];   // [k][n]
  const int tid = threadIdx.x;
  const int bm = blockIdx.x, bn = blockIdx.y;
  const int ty = tid >> 4, tx = tid & 15;
  const int arow = tid >> 2, acol = (tid & 3) << 2;
  const int wrow = tid >> 4, wcol = (tid & 15) << 2;
  const float* Ag = A + (size_t)(bm * 64 + arow) * K + acol;
  const float* Wg = W + (size_t)wrow * N + bn * 64 + wcol;
  float acc[4][4] = {};
  for (int k0 = 0; k0 < K; k0 += 16) {
    float4 av = *(const float4*)(Ag + k0);
    float4 wv = *(const float4*)(Wg + (size_t)k0 * N);
    __syncthreads();
    As[acol + 0][arow] = av.x;
    As[acol + 1][arow] = av.y;
    As[acol + 2][arow] = av.z;
    As[acol + 3][arow] = av.w;
    *(float4*)&Ws[wrow][wcol] = wv;
    __syncthreads();
#pragma unroll
    for (int kk = 0; kk < 16; ++kk) {
      float4 a = *(const float4*)&As[kk][ty << 2];
      float4 b = *(const float4*)&Ws[kk][tx << 2];
      acc[0][0] += a.x * b.x; acc[0][1] += a.x * b.y; acc[0][2] += a.x * b.z; acc[0][3] += a.x * b.w;
      acc[1][0] += a.y * b.x; acc[1][1] += a.y * b.y; acc[1][2] += a.y * b.z; acc[1][3] += a.y * b.w;
      acc[2][0] += a.z * b.x; acc[2][1] += a.z * b.y; acc[2][2] += a.z * b.z; acc[2][3] += a.z * b.w;
      acc[3][0] += a.w * b.x; acc[3][1] += a.w * b.y; acc[3][2] += a.w * b.z; acc[3][3] += a.w * b.w;
    }
  }
  const int col = bn * 64 + (tx << 2);
  float4 bv = *(const float4*)&bias[col];
#pragma unroll
  for (int i = 0; i < 4; ++i) {
    int row = bm * 64 + (ty << 2) + i;
    float4 o;
    o.x = acc[i][0] + bv.x; o.y = acc[i][1] + bv.y;
    o.z = acc[i][2] + bv.z; o.w = acc[i][3] + bv.w;
    *(float4*)&C[(size_t)row * N + col] = o;
  }
}

// ---------------------------------------------------------------------------
// Causal local-window (L=5) softmax pooling. One wave per position.
// Padded (s-4+j < 0) rows contribute score exactly 0 and a zero vector,
// but their softmax weight exp(0-m)/Z still participates — matches reference.
// ---------------------------------------------------------------------------
__global__ __launch_bounds__(256) void local_pool_kernel(
    const float* __restrict__ x, float* __restrict__ out) {
  const int gtid = blockIdx.x * 256 + threadIdx.x;
  const int wave = gtid >> 6;      // global position index in [0, B*S)
  const int lane = gtid & 63;
  if (wave >= BS_) return;
  const int b = wave / S_, s = wave % S_;
  const float* xrow = x + ((size_t)b * S_ + s) * D_;
  const int d0 = lane * 8;         // 8 dims per lane (512/64)
  float xi[8];
  *(float4*)&xi[0] = *(const float4*)&xrow[d0];
  *(float4*)&xi[4] = *(const float4*)&xrow[d0 + 4];
  float win[5][8];
  float sc[5];
#pragma unroll
  for (int j = 0; j < 5; ++j) {
    int src = s - 4 + j;
    float part = 0.f;
    if (src >= 0) {
      const float* wr = x + ((size_t)b * S_ + src) * D_;
      *(float4*)&win[j][0] = *(const float4*)&wr[d0];
      *(float4*)&win[j][4] = *(const float4*)&wr[d0 + 4];
#pragma unroll
      for (int t = 0; t < 8; ++t) part += xi[t] * win[j][t];
    } else {
#pragma unroll
      for (int t = 0; t < 8; ++t) win[j][t] = 0.f;
    }
    sc[j] = part;
  }
  // butterfly reduce each of the 5 dots across the 64-lane wave
#pragma unroll
  for (int off = 1; off < 64; off <<= 1) {
#pragma unroll
    for (int j = 0; j < 5; ++j) sc[j] += __shfl_xor(sc[j], off, 64);
  }
  const float scale = 0.04419417382415922f;  // 1/sqrt(512)
  float m = sc[0] * scale;
#pragma unroll
  for (int j = 1; j < 5; ++j) m = fmaxf(m, sc[j] * scale);
  float w[5], lsum = 0.f;
#pragma unroll
  for (int j = 0; j < 5; ++j) { w[j] = expf(sc[j] * scale - m); lsum += w[j]; }
  const float inv = 1.f / lsum;
  float o[8] = {0.f, 0.f, 0.f, 0.f, 0.f, 0.f, 0.f, 0.f};
#pragma unroll
  for (int j = 0; j < 5; ++j)
#pragma unroll
    for (int t = 0; t < 8; ++t) o[t] += w[j] * win[j][t];
  float* orow = out + ((size_t)b * S_ + s) * D_;
  float4 o0, o1;
  o0.x = o[0] * inv; o0.y = o[1] * inv; o0.z = o[2] * inv; o0.w = o[3] * inv;
  o1.x = o[4] * inv; o1.y = o[5] * inv; o1.z = o[6] * inv; o1.w = o[7] * inv;
  *(float4*)&orow[d0] = o0;
  *(float4*)&orow[d0 + 4] = o1;
}

// ---------------------------------------------------------------------------
// Flash-style f32 attention. Block = 256 threads = one (b, h, 64-row q-tile).
// 4 threads per q-row (g = d-group of 16 dims). Full 2048-key softmax, no mask.
// x output may alias q (each thread reads exactly the q elems it later writes).
// ---------------------------------------------------------------------------
__global__ __launch_bounds__(256) void attn_kernel(
    const float* __restrict__ q, const float* __restrict__ k,
    const float* __restrict__ v, float* __restrict__ x) {
  const int bid = blockIdx.x;
  const int qt = bid & 31;          // S/64 = 32 q-tiles
  const int h  = (bid >> 5) & 7;
  const int b  = bid >> 8;
  const int tid = threadIdx.x;
  const int r = tid >> 2;           // q-row within tile, 0..63
  const int g = tid & 3;            // 16-dim group
  __shared__ float ks[64][64];
  __shared__ float vs[64][64];

  float qreg[16];
  const float* qrow = q + ((size_t)b * S_ + qt * 64 + r) * D_ + h * DK_ + g * 16;
#pragma unroll
  for (int i = 0; i < 4; ++i)
    *(float4*)&qreg[i * 4] = *(const float4*)&qrow[i * 4];

  float acc[16] = {};
  float mrow = -INFINITY, lrow = 0.f;
  const float scale = 0.125f;       // 1/sqrt(64)

  const int lr = tid >> 2;          // load row 0..63
  const int lc = (tid & 3) << 4;    // load col group: 0,16,32,48

  for (int kt = 0; kt < 32; ++kt) {
    __syncthreads();
    {
      const float* kga = k + ((size_t)b * S_ + kt * 64 + lr) * D_ + h * DK_ + lc;
      const float* vga = v + ((size_t)b * S_ + kt * 64 + lr) * D_ + h * DK_ + lc;
#pragma unroll
      for (int i = 0; i < 4; ++i) {
        *(float4*)&ks[lr][lc + i * 4] = *(const float4*)&kga[i * 4];
        *(float4*)&vs[lr][lc + i * 4] = *(const float4*)&vga[i * 4];
      }
    }
    __syncthreads();

    // partial scores over this thread's 16 dims, for all 64 keys
    float s[64];
#pragma unroll
    for (int kk = 0; kk < 64; ++kk) {
      const float* kr = &ks[kk][g << 4];
      float p = 0.f;
#pragma unroll
      for (int dd = 0; dd < 4; ++dd) {
        float4 kv = *(const float4*)&kr[dd * 4];
        p += qreg[dd * 4 + 0] * kv.x + qreg[dd * 4 + 1] * kv.y +
             qreg[dd * 4 + 2] * kv.z + qreg[dd * 4 + 3] * kv.w;
      }
      s[kk] = p;
    }
    // combine the 4 d-group partials (lanes differ in low 2 bits)
#pragma unroll
    for (int kk = 0; kk < 64; ++kk) {
      s[kk] += __shfl_xor(s[kk], 1, 64);
      s[kk] += __shfl_xor(s[kk], 2, 64);
    }
    // online softmax (all 4 g-threads hold identical full scores)
    float tmax = s[0];
#pragma unroll
    for (int kk = 1; kk < 64; ++kk) tmax = fmaxf(tmax, s[kk]);
    tmax *= scale;
    const float mnew = fmaxf(mrow, tmax);
    const float corr = expf(mrow - mnew);   // first tile: exp(-inf)=0
    float psum = 0.f;
#pragma unroll
    for (int kk = 0; kk < 64; ++kk) {
      s[kk] = expf(s[kk] * scale - mnew);
      psum += s[kk];
    }
    lrow = lrow * corr + psum;
    mrow = mnew;
#pragma unroll
    for (int d = 0; d < 16; ++d) acc[d] *= corr;
    // acc += P @ V over this tile
#pragma unroll
    for (int kk = 0; kk < 64; ++kk) {
      const float* vr = &vs[kk][g << 4];
      const float pk = s[kk];
#pragma unroll
      for (int dd = 0; dd < 4; ++dd) {
        float4 vv = *(const float4*)&vr[dd * 4];
        acc[dd * 4 + 0] += pk * vv.x;
        acc[dd * 4 + 1] += pk * vv.y;
        acc[dd * 4 + 2] += pk * vv.z;
        acc[dd * 4 + 3] += pk * vv.w;
      }
    }
  }
  const float inv = 1.f / lrow;
  float* xrow = x + ((size_t)b * S_ + qt * 64 + r) * D_ + h * DK_ + g * 16;
#pragma unroll
  for (int i = 0; i < 4; ++i) {
    float4 o;
    o.x = acc[i * 4 + 0] * inv; o.y = acc[i * 4 + 1] * inv;
    o.z = acc[i * 4 + 2] * inv; o.w = acc[i * 4 + 3] * inv;
    *(float4*)&xrow[i * 4] = o;
  }
}

// ---------------------------------------------------------------------------
extern "C" void kernel_launch(void* const* d_in, const int* in_sizes, int n_in,
                              void* d_out, int out_size, void* d_ws, size_t ws_size,
                              hipStream_t stream) {
  const float* query = (const float*)d_in[0];
  const float* key   = (const float*)d_in[1];
  const float* value = (const float*)d_in[2];
  // d_in[3] = mask (all ones; unused by the reference)
  const float* W_fk = (const float*)d_in[4];
  const float* b_fk = (const float*)d_in[5];
  const float* W0   = (const float*)d_in[6];
  const float* b0   = (const float*)d_in[7];
  const float* Wout = (const float*)d_in[8];
  const float* bout = (const float*)d_in[9];
  float* out = (float*)d_out;

  float* ws = (float*)d_ws;
  const size_t buf = (size_t)BS_ * D_;   // 4M floats = 16MB
  float* t_ws  = ws;            // kfk, then v
  float* kp_ws = ws + buf;      // pooled k
  float* q_ws  = ws + 2 * buf;  // pooled q, then attention output (aliased)

  dim3 gblk(256), ggrid(BS_ / 64, D_ / 64);
  dim3 pgrid(BS_ * 64 / 256);

  // kfk = key @ W_fk + b_fk
  gemm_bias_kernel<<<ggrid, gblk, 0, stream>>>(key, W_fk, b_fk, t_ws);
  // kp = local_pool(kfk)
  local_pool_kernel<<<pgrid, 256, 0, stream>>>(t_ws, kp_ws);
  // v = value @ W0 + b0 (overwrites kfk)
  gemm_bias_kernel<<<ggrid, gblk, 0, stream>>>(value, W0, b0, t_ws);
  // qp = local_pool(query)
  local_pool_kernel<<<pgrid, 256, 0, stream>>>(query, q_ws);
  // x = attention(qp, kp, v)  (writes over q_ws; per-thread exact aliasing)
  attn_kernel<<<dim3(B_ * H_ * (S_ / 64)), 256, 0, stream>>>(q_ws, kp_ws, t_ws, q_ws);
  // out = x @ Wout + bout
  gemm_bias_kernel<<<ggrid, gblk, 0, stream>>>(q_ws, Wout, bout, out);
}

// Round 2
// 311.982 us; speedup vs baseline: 4.9293x; 4.9293x over previous
//
#include <hip/hip_runtime.h>
#include <hip/hip_bf16.h>
#include <math.h>

#define B_  4
#define S_  2048
#define D_  512
#define H_  8
#define DK_ 64
#define BS_ (B_*S_)

using bf16x8 = __attribute__((ext_vector_type(8))) short;
using f32x4  = __attribute__((ext_vector_type(4))) float;

static __device__ inline unsigned pk2(float a, float b) {
  union { __hip_bfloat16 h; unsigned short u; } x, y;
  x.h = __float2bfloat16(a); y.h = __float2bfloat16(b);
  return (unsigned)x.u | ((unsigned)y.u << 16);
}
static __device__ inline unsigned short f2bf(float a) {
  union { __hip_bfloat16 h; unsigned short u; } x;
  x.h = __float2bfloat16(a); return x.u;
}

// ---------------------------------------------------------------------------
// GEMM: C[M,512] = A[M,512] @ W[512,512] + bias (f32 compute; bf16 or f32 out)
// ---------------------------------------------------------------------------
template <int BF16OUT>
__global__ __launch_bounds__(256) void gemm_bias_kernel(
    const float* __restrict__ A, const float* __restrict__ W,
    const float* __restrict__ bias, void* __restrict__ Cv) {
  constexpr int K = D_, N = D_;
  __shared__ float As[16][72];
  __shared__ float Ws[16][72];
  const int tid = threadIdx.x;
  const int bm = blockIdx.x, bn = blockIdx.y;
  const int ty = tid >> 4, tx = tid & 15;
  const int arow = tid >> 2, acol = (tid & 3) << 2;
  const int wrow = tid >> 4, wcol = (tid & 15) << 2;
  const float* Ag = A + (size_t)(bm * 64 + arow) * K + acol;
  const float* Wg = W + (size_t)wrow * N + bn * 64 + wcol;
  float acc[4][4] = {};
  for (int k0 = 0; k0 < K; k0 += 16) {
    float4 av = *(const float4*)(Ag + k0);
    float4 wv = *(const float4*)(Wg + (size_t)k0 * N);
    __syncthreads();
    As[acol + 0][arow] = av.x;
    As[acol + 1][arow] = av.y;
    As[acol + 2][arow] = av.z;
    As[acol + 3][arow] = av.w;
    *(float4*)&Ws[wrow][wcol] = wv;
    __syncthreads();
#pragma unroll
    for (int kk = 0; kk < 16; ++kk) {
      float4 a = *(const float4*)&As[kk][ty << 2];
      float4 b = *(const float4*)&Ws[kk][tx << 2];
      acc[0][0] += a.x * b.x; acc[0][1] += a.x * b.y; acc[0][2] += a.x * b.z; acc[0][3] += a.x * b.w;
      acc[1][0] += a.y * b.x; acc[1][1] += a.y * b.y; acc[1][2] += a.y * b.z; acc[1][3] += a.y * b.w;
      acc[2][0] += a.z * b.x; acc[2][1] += a.z * b.y; acc[2][2] += a.z * b.z; acc[2][3] += a.z * b.w;
      acc[3][0] += a.w * b.x; acc[3][1] += a.w * b.y; acc[3][2] += a.w * b.z; acc[3][3] += a.w * b.w;
    }
  }
  const int col = bn * 64 + (tx << 2);
  float4 bv = *(const float4*)&bias[col];
#pragma unroll
  for (int i = 0; i < 4; ++i) {
    int row = bm * 64 + (ty << 2) + i;
    float o0 = acc[i][0] + bv.x, o1 = acc[i][1] + bv.y;
    float o2 = acc[i][2] + bv.z, o3 = acc[i][3] + bv.w;
    if (BF16OUT) {
      unsigned short* C = (unsigned short*)Cv;
      uint2 pk;
      pk.x = pk2(o0, o1); pk.y = pk2(o2, o3);
      *(uint2*)&C[(size_t)row * N + col] = pk;
    } else {
      float* C = (float*)Cv;
      float4 o; o.x = o0; o.y = o1; o.z = o2; o.w = o3;
      *(float4*)&C[(size_t)row * N + col] = o;
    }
  }
}

// ---------------------------------------------------------------------------
// Causal local-window (L=5) softmax pooling; f32 in, bf16 out (scaled).
// Padded rows: score 0, zero vector (matches reference zero-pad semantics).
// ---------------------------------------------------------------------------
__global__ __launch_bounds__(256) void local_pool_kernel(
    const float* __restrict__ x, unsigned short* __restrict__ out,
    float oscale) {
  const int gtid = blockIdx.x * 256 + threadIdx.x;
  const int wave = gtid >> 6;
  const int lane = gtid & 63;
  if (wave >= BS_) return;
  const int b = wave / S_, s = wave % S_;
  const float* xrow = x + ((size_t)b * S_ + s) * D_;
  const int d0 = lane * 8;
  float xi[8];
  *(float4*)&xi[0] = *(const float4*)&xrow[d0];
  *(float4*)&xi[4] = *(const float4*)&xrow[d0 + 4];
  float win[5][8];
  float sc[5];
#pragma unroll
  for (int j = 0; j < 5; ++j) {
    int src = s - 4 + j;
    float part = 0.f;
    if (src >= 0) {
      const float* wr = x + ((size_t)b * S_ + src) * D_;
      *(float4*)&win[j][0] = *(const float4*)&wr[d0];
      *(float4*)&win[j][4] = *(const float4*)&wr[d0 + 4];
#pragma unroll
      for (int t = 0; t < 8; ++t) part += xi[t] * win[j][t];
    } else {
#pragma unroll
      for (int t = 0; t < 8; ++t) win[j][t] = 0.f;
    }
    sc[j] = part;
  }
#pragma unroll
  for (int off = 1; off < 64; off <<= 1) {
#pragma unroll
    for (int j = 0; j < 5; ++j) sc[j] += __shfl_xor(sc[j], off, 64);
  }
  const float scale = 0.04419417382415922f;  // 1/sqrt(512)
  float m = sc[0] * scale;
#pragma unroll
  for (int j = 1; j < 5; ++j) m = fmaxf(m, sc[j] * scale);
  float w[5], lsum = 0.f;
#pragma unroll
  for (int j = 0; j < 5; ++j) { w[j] = expf(sc[j] * scale - m); lsum += w[j]; }
  const float inv = oscale / lsum;
  float o[8] = {};
#pragma unroll
  for (int j = 0; j < 5; ++j)
#pragma unroll
    for (int t = 0; t < 8; ++t) o[t] += w[j] * win[j][t];
  unsigned short* orow = out + ((size_t)b * S_ + s) * D_;
  uint4 pk;
  pk.x = pk2(o[0] * inv, o[1] * inv);
  pk.y = pk2(o[2] * inv, o[3] * inv);
  pk.z = pk2(o[4] * inv, o[5] * inv);
  pk.w = pk2(o[6] * inv, o[7] * inv);
  *(uint4*)&orow[d0] = pk;
}

// ---------------------------------------------------------------------------
// MFMA flash attention (bf16 in, f32 out). Block = 4 waves x 32 q-rows = 128
// q-rows per block; KV tiles of 64. Swapped QK^T: S^T = mfma(K, Q) so each
// lane's column is one q-row (col=lane&15), rows are keys ((lane>>4)*4+reg).
// q comes in pre-scaled by 1/sqrt(dk).
// ---------------------------------------------------------------------------
__global__ __launch_bounds__(256) void attn_mfma_kernel(
    const unsigned short* __restrict__ q, const unsigned short* __restrict__ k,
    const unsigned short* __restrict__ v, float* __restrict__ x) {
  const int bid = blockIdx.x;          // 512 = b(4) * h(8) * qt(16)
  const int qt = bid & 15;
  const int h  = (bid >> 4) & 7;
  const int b  = bid >> 7;
  const int tid = threadIdx.x;
  const int wv = tid >> 6, lane = tid & 63;
  const int c = lane & 15, g = lane >> 4;

  __shared__ unsigned short Ks[64][80];   // [key][feat], padded
  __shared__ unsigned short Vt[64][80];   // [d][key], padded

  // Q fragments: 2 row-tiles x 2 feature-steps (B-operand: col=q=c, k=8g+j)
  bf16x8 Qf[2][2];
  const size_t qbase = ((size_t)b * S_ + qt * 128 + wv * 32) * D_ + h * 64;
#pragma unroll
  for (int rt = 0; rt < 2; ++rt)
#pragma unroll
    for (int fs = 0; fs < 2; ++fs)
      Qf[rt][fs] = *(const bf16x8*)(q + qbase + (size_t)(rt * 16 + c) * D_ + fs * 32 + g * 8);

  f32x4 acc[2][4];
#pragma unroll
  for (int rt = 0; rt < 2; ++rt)
#pragma unroll
    for (int ds = 0; ds < 4; ++ds) acc[rt][ds] = f32x4{0.f, 0.f, 0.f, 0.f};
  float mrow[2] = {-INFINITY, -INFINITY}, lrow[2] = {0.f, 0.f};

  const int kk = tid >> 2, kf = (tid & 3) << 4;    // K staging: row, 16-feat group
  const int vd = tid & 63, vh = tid >> 6;          // V staging: d-column, key-group

  for (int kt = 0; kt < S_ / 64; ++kt) {
    const int kb = kt * 64;
    __syncthreads();
    {  // stage K[64][64] row-major
      const unsigned short* kg_ = k + ((size_t)b * S_ + kb + kk) * D_ + h * 64 + kf;
      *(uint4*)&Ks[kk][kf]     = *(const uint4*)kg_;
      *(uint4*)&Ks[kk][kf + 8] = *(const uint4*)(kg_ + 8);
    }
    {  // stage V transposed: Vt[d][key]
      const unsigned short* vg_ = v + ((size_t)b * S_ + kb + vh * 16) * D_ + h * 64 + vd;
      unsigned short tmp[16];
#pragma unroll
      for (int i = 0; i < 16; ++i) tmp[i] = vg_[(size_t)i * D_];
      *(uint4*)&Vt[vd][vh * 16]     = *(uint4*)&tmp[0];
      *(uint4*)&Vt[vd][vh * 16 + 8] = *(uint4*)&tmp[8];
    }
    __syncthreads();

#pragma unroll
    for (int rt = 0; rt < 2; ++rt) {
      // ---- QK^T: S^T[key=16ks+4g+reg][q=c] ----
      f32x4 sf[4];
#pragma unroll
      for (int ks = 0; ks < 4; ++ks) {
        bf16x8 ka0 = *(const bf16x8*)&Ks[ks * 16 + c][g * 8];
        bf16x8 ka1 = *(const bf16x8*)&Ks[ks * 16 + c][32 + g * 8];
        f32x4 z = f32x4{0.f, 0.f, 0.f, 0.f};
        z = __builtin_amdgcn_mfma_f32_16x16x32_bf16(ka0, Qf[rt][0], z, 0, 0, 0);
        z = __builtin_amdgcn_mfma_f32_16x16x32_bf16(ka1, Qf[rt][1], z, 0, 0, 0);
        sf[ks] = z;
      }
      // ---- online softmax over this tile's 64 keys (per q-column c) ----
      float mt = sf[0][0];
#pragma unroll
      for (int st = 0; st < 4; ++st)
#pragma unroll
        for (int r = 0; r < 4; ++r) mt = fmaxf(mt, sf[st][r]);
      mt = fmaxf(mt, __shfl_xor(mt, 16, 64));
      mt = fmaxf(mt, __shfl_xor(mt, 32, 64));
      const float mnew = fmaxf(mrow[rt], mt);
      const float corr = __expf(mrow[rt] - mnew);
      float p[4][4];
      float ts = 0.f;
#pragma unroll
      for (int st = 0; st < 4; ++st)
#pragma unroll
        for (int r = 0; r < 4; ++r) { p[st][r] = __expf(sf[st][r] - mnew); ts += p[st][r]; }
      ts += __shfl_xor(ts, 16, 64);
      ts += __shfl_xor(ts, 32, 64);
      lrow[rt] = lrow[rt] * corr + ts;
      mrow[rt] = mnew;
#pragma unroll
      for (int ds = 0; ds < 4; ++ds) {
        acc[rt][ds][0] *= corr; acc[rt][ds][1] *= corr;
        acc[rt][ds][2] *= corr; acc[rt][ds][3] *= corr;
      }
      // ---- PV: out^T += V^T . P^T, two 32-key steps ----
#pragma unroll
      for (int pr = 0; pr < 2; ++pr) {
        // own words w[s2][h] = keys 16*(2pr+s2)+4g+2h,+1 for col q=c
        unsigned w00 = pk2(p[2 * pr][0], p[2 * pr][1]);
        unsigned w01 = pk2(p[2 * pr][2], p[2 * pr][3]);
        unsigned w10 = pk2(p[2 * pr + 1][0], p[2 * pr + 1][1]);
        unsigned w11 = pk2(p[2 * pr + 1][2], p[2 * pr + 1][3]);
        // exchange so lane holds keys 8g..8g+7 (B-operand layout)
        unsigned n00 = __shfl_xor(w00, 16, 64), n01 = __shfl_xor(w01, 16, 64);
        unsigned n10 = __shfl_xor(w10, 16, 64), n11 = __shfl_xor(w11, 16, 64);
        const bool odd = (g & 1);
        unsigned pe00 = odd ? n00 : w00, pe01 = odd ? n01 : w01;
        unsigned pe10 = odd ? n10 : w10, pe11 = odd ? n11 : w11;
        unsigned po00 = odd ? w00 : n00, po01 = odd ? w01 : n01;
        unsigned po10 = odd ? w10 : n10, po11 = odd ? w11 : n11;
        unsigned qe00 = __shfl_xor(pe00, 32, 64), qe01 = __shfl_xor(pe01, 32, 64);
        unsigned qe10 = __shfl_xor(pe10, 32, 64), qe11 = __shfl_xor(pe11, 32, 64);
        unsigned qo00 = __shfl_xor(po00, 32, 64), qo01 = __shfl_xor(po01, 32, 64);
        unsigned qo10 = __shfl_xor(po10, 32, 64), qo11 = __shfl_xor(po11, 32, 64);
        const bool need = (g == 1) || (g == 2);
        unsigned re00 = need ? qe00 : pe00, re01 = need ? qe01 : pe01;
        unsigned re10 = need ? qe10 : pe10, re11 = need ? qe11 : pe11;
        unsigned ro00 = need ? qo00 : po00, ro01 = need ? qo01 : po01;
        unsigned ro10 = need ? qo10 : po10, ro11 = need ? qo11 : po11;
        const bool hi = (g >> 1);
        union { unsigned u[4]; bf16x8 v; } pb;
        pb.u[0] = hi ? re10 : re00;
        pb.u[1] = hi ? re11 : re01;
        pb.u[2] = hi ? ro10 : ro00;
        pb.u[3] = hi ? ro11 : ro01;
#pragma unroll
        for (int ds = 0; ds < 4; ++ds) {
          bf16x8 va = *(const bf16x8*)&Vt[ds * 16 + c][pr * 32 + g * 8];
          acc[rt][ds] = __builtin_amdgcn_mfma_f32_16x16x32_bf16(va, pb.v, acc[rt][ds], 0, 0, 0);
        }
      }
    }
  }
  // epilogue: x[q][d], q = base+c, d = 16ds + 4g + r
#pragma unroll
  for (int rt = 0; rt < 2; ++rt) {
    const float inv = 1.f / lrow[rt];
    float* xrow = x + ((size_t)b * S_ + qt * 128 + wv * 32 + rt * 16 + c) * D_ + h * 64;
#pragma unroll
    for (int ds = 0; ds < 4; ++ds)
#pragma unroll
      for (int r = 0; r < 4; ++r)
        xrow[ds * 16 + 4 * g + r] = acc[rt][ds][r] * inv;
  }
}

// ---------------------------------------------------------------------------
extern "C" void kernel_launch(void* const* d_in, const int* in_sizes, int n_in,
                              void* d_out, int out_size, void* d_ws, size_t ws_size,
                              hipStream_t stream) {
  const float* query = (const float*)d_in[0];
  const float* key   = (const float*)d_in[1];
  const float* value = (const float*)d_in[2];
  const float* W_fk = (const float*)d_in[4];
  const float* b_fk = (const float*)d_in[5];
  const float* W0   = (const float*)d_in[6];
  const float* b0   = (const float*)d_in[7];
  const float* Wout = (const float*)d_in[8];
  const float* bout = (const float*)d_in[9];
  float* out = (float*)d_out;

  char* ws = (char*)d_ws;
  float* kfk_f32   = (float*)ws;                       // 16MB @ 0 (later q_bf16)
  float* x_f32     = (float*)(ws + (16u << 20));       // 16MB @ 16MB
  unsigned short* k_bf16 = (unsigned short*)(ws + (32u << 20));  // 8MB @ 32MB
  unsigned short* v_bf16 = (unsigned short*)(ws + (40u << 20));  // 8MB @ 40MB
  unsigned short* q_bf16 = (unsigned short*)ws;        // overlays kfk after use

  dim3 gblk(256), ggrid(BS_ / 64, D_ / 64);
  dim3 pgrid(BS_ * 64 / 256);
  const float qscale = 0.125f;  // 1/sqrt(dk): folded into pooled q

  // kfk = key @ W_fk + b_fk (f32)
  gemm_bias_kernel<0><<<ggrid, gblk, 0, stream>>>(key, W_fk, b_fk, kfk_f32);
  // k = pool(kfk) -> bf16
  local_pool_kernel<<<pgrid, 256, 0, stream>>>(kfk_f32, k_bf16, 1.0f);
  // v = value @ W0 + b0 -> bf16
  gemm_bias_kernel<1><<<ggrid, gblk, 0, stream>>>(value, W0, b0, v_bf16);
  // q = pool(query) * 0.125 -> bf16 (overwrites kfk region)
  local_pool_kernel<<<pgrid, 256, 0, stream>>>(query, q_bf16, qscale);
  // x = attention(q, k, v) -> f32
  attn_mfma_kernel<<<dim3(B_ * H_ * (S_ / 128)), 256, 0, stream>>>(q_bf16, k_bf16, v_bf16, x_f32);
  // out = x @ Wout + bout (f32)
  gemm_bias_kernel<0><<<ggrid, gblk, 0, stream>>>(x_f32, Wout, bout, out);
}

// Round 3
// 218.498 us; speedup vs baseline: 7.0383x; 1.4279x over previous
//
#include <hip/hip_runtime.h>
#include <hip/hip_bf16.h>
#include <math.h>

#define B_  4
#define S_  2048
#define D_  512
#define H_  8
#define DK_ 64
#define BS_ (B_*S_)

using bf16x8 = __attribute__((ext_vector_type(8))) short;
using f32x4  = __attribute__((ext_vector_type(4))) float;

static __device__ inline unsigned short f2bf(float a) {
  union { __hip_bfloat16 h; unsigned short u; } x;
  x.h = __float2bfloat16(a); return x.u;
}
static __device__ inline float bf16f(unsigned short u) {
  union { unsigned u32; float f; } x; x.u32 = (unsigned)u << 16; return x.f;
}
static __device__ inline unsigned pk2(float a, float b) {
  return (unsigned)f2bf(a) | ((unsigned)f2bf(b) << 16);
}

// ---------------------------------------------------------------------------
// MFMA GEMM: C[M=8192,512] = A[M,512] @ W[512,512] + bias.
// A,W f32 in global, converted to bf16 (hi, + lo residual if SPLIT) during
// LDS staging. SPLIT=1: acc = Ah*Wh + Ah*Wl + Al*Wh  (~f32 accuracy, 3x MFMA).
// Tiles: BM=128, BN=64, BK=64; 4 waves; wave -> 32 rows x 64 cols.
// W staged transposed (Wt[n][k]) as the MFMA A-operand so D = C[m][n] with
// n contiguous per lane (coalesced 16B stores).
// ---------------------------------------------------------------------------
template <int SPLIT, int BF16OUT>
__global__ __launch_bounds__(256) void gemm_mfma_kernel(
    const float* __restrict__ A, const float* __restrict__ W,
    const float* __restrict__ bias, void* __restrict__ Cv) {
  const int bn = blockIdx.x;      // 8
  const int bm = blockIdx.y;      // 64
  const int tid = threadIdx.x;
  const int wv = tid >> 6, lane = tid & 63;
  const int c = lane & 15, g = lane >> 4;

  __shared__ unsigned short As[SPLIT + 1][128][72];  // [hi/lo][m][k]
  __shared__ unsigned short Wt[SPLIT + 1][64][72];   // [hi/lo][n][k]

  f32x4 acc[2][4];
#pragma unroll
  for (int rt = 0; rt < 2; ++rt)
#pragma unroll
    for (int ds = 0; ds < 4; ++ds) acc[rt][ds] = f32x4{0.f, 0.f, 0.f, 0.f};

  const int arow = tid >> 1, ah = (tid & 1) * 32;   // A stage: row, 32-k half
  const int wn = tid & 63, wkg = (tid >> 6) * 16;   // W stage: col, 16-k group

  for (int k0 = 0; k0 < D_; k0 += 64) {
    // ---- global loads (f32) ----
    float af[32];
    const float* ag = A + ((size_t)(bm * 128 + arow)) * D_ + k0 + ah;
#pragma unroll
    for (int i = 0; i < 8; ++i) *(float4*)&af[i * 4] = *(const float4*)(ag + i * 4);
    float wf[16];
    const float* wg = W + (size_t)(k0 + wkg) * D_ + bn * 64 + wn;
#pragma unroll
    for (int i = 0; i < 16; ++i) wf[i] = wg[(size_t)i * D_];

    __syncthreads();   // previous compute done before overwriting LDS
    // ---- pack + LDS write: A ----
#pragma unroll
    for (int grp = 0; grp < 4; ++grp) {
      unsigned h[4], l[4];
#pragma unroll
      for (int p = 0; p < 4; ++p) {
        float f0 = af[grp * 8 + p * 2], f1 = af[grp * 8 + p * 2 + 1];
        unsigned short h0 = f2bf(f0), h1 = f2bf(f1);
        h[p] = (unsigned)h0 | ((unsigned)h1 << 16);
        if constexpr (SPLIT) l[p] = pk2(f0 - bf16f(h0), f1 - bf16f(h1));
      }
      uint4 uh; uh.x = h[0]; uh.y = h[1]; uh.z = h[2]; uh.w = h[3];
      *(uint4*)&As[0][arow][ah + grp * 8] = uh;
      if constexpr (SPLIT) {
        uint4 ul; ul.x = l[0]; ul.y = l[1]; ul.z = l[2]; ul.w = l[3];
        *(uint4*)&As[1][arow][ah + grp * 8] = ul;
      }
    }
    // ---- pack + LDS write: W^T ----
#pragma unroll
    for (int grp = 0; grp < 2; ++grp) {
      unsigned h[4], l[4];
#pragma unroll
      for (int p = 0; p < 4; ++p) {
        float f0 = wf[grp * 8 + p * 2], f1 = wf[grp * 8 + p * 2 + 1];
        unsigned short h0 = f2bf(f0), h1 = f2bf(f1);
        h[p] = (unsigned)h0 | ((unsigned)h1 << 16);
        if constexpr (SPLIT) l[p] = pk2(f0 - bf16f(h0), f1 - bf16f(h1));
      }
      uint4 uh; uh.x = h[0]; uh.y = h[1]; uh.z = h[2]; uh.w = h[3];
      *(uint4*)&Wt[0][wn][wkg + grp * 8] = uh;
      if constexpr (SPLIT) {
        uint4 ul; ul.x = l[0]; ul.y = l[1]; ul.z = l[2]; ul.w = l[3];
        *(uint4*)&Wt[1][wn][wkg + grp * 8] = ul;
      }
    }
    __syncthreads();

    // ---- MFMA: acc[rt][ds] over 2 ksubs ----
#pragma unroll
    for (int ksub = 0; ksub < 2; ++ksub) {
      bf16x8 bh[2], bl[2];
#pragma unroll
      for (int rt = 0; rt < 2; ++rt) {
        bh[rt] = *(const bf16x8*)&As[0][wv * 32 + rt * 16 + c][ksub * 32 + g * 8];
        if constexpr (SPLIT)
          bl[rt] = *(const bf16x8*)&As[1][wv * 32 + rt * 16 + c][ksub * 32 + g * 8];
      }
#pragma unroll
      for (int ds = 0; ds < 4; ++ds) {
        bf16x8 ah_ = *(const bf16x8*)&Wt[0][ds * 16 + c][ksub * 32 + g * 8];
#pragma unroll
        for (int rt = 0; rt < 2; ++rt)
          acc[rt][ds] = __builtin_amdgcn_mfma_f32_16x16x32_bf16(ah_, bh[rt], acc[rt][ds], 0, 0, 0);
        if constexpr (SPLIT) {
          bf16x8 al_ = *(const bf16x8*)&Wt[1][ds * 16 + c][ksub * 32 + g * 8];
#pragma unroll
          for (int rt = 0; rt < 2; ++rt) {
            acc[rt][ds] = __builtin_amdgcn_mfma_f32_16x16x32_bf16(ah_, bl[rt], acc[rt][ds], 0, 0, 0);
            acc[rt][ds] = __builtin_amdgcn_mfma_f32_16x16x32_bf16(al_, bh[rt], acc[rt][ds], 0, 0, 0);
          }
        }
      }
    }
  }

  // ---- epilogue: C[m][n], m = bm*128+wv*32+rt*16+c, n = bn*64+ds*16+4g+r ----
#pragma unroll
  for (int rt = 0; rt < 2; ++rt) {
    const size_t m = (size_t)bm * 128 + wv * 32 + rt * 16 + c;
#pragma unroll
    for (int ds = 0; ds < 4; ++ds) {
      const int n = bn * 64 + ds * 16 + 4 * g;
      float4 bv = *(const float4*)&bias[n];
      float o0 = acc[rt][ds][0] + bv.x, o1 = acc[rt][ds][1] + bv.y;
      float o2 = acc[rt][ds][2] + bv.z, o3 = acc[rt][ds][3] + bv.w;
      if constexpr (BF16OUT) {
        uint2 p; p.x = pk2(o0, o1); p.y = pk2(o2, o3);
        *(uint2*)((unsigned short*)Cv + m * D_ + n) = p;
      } else {
        float4 o; o.x = o0; o.y = o1; o.z = o2; o.w = o3;
        *(float4*)((float*)Cv + m * D_ + n) = o;
      }
    }
  }
}

// ---------------------------------------------------------------------------
// Causal local-window (L=5) softmax pooling; f32 in, bf16 out (scaled).
// ---------------------------------------------------------------------------
__global__ __launch_bounds__(256) void local_pool_kernel(
    const float* __restrict__ x, unsigned short* __restrict__ out,
    float oscale) {
  const int gtid = blockIdx.x * 256 + threadIdx.x;
  const int wave = gtid >> 6;
  const int lane = gtid & 63;
  if (wave >= BS_) return;
  const int b = wave / S_, s = wave % S_;
  const float* xrow = x + ((size_t)b * S_ + s) * D_;
  const int d0 = lane * 8;
  float xi[8];
  *(float4*)&xi[0] = *(const float4*)&xrow[d0];
  *(float4*)&xi[4] = *(const float4*)&xrow[d0 + 4];
  float win[5][8];
  float sc[5];
#pragma unroll
  for (int j = 0; j < 5; ++j) {
    int src = s - 4 + j;
    float part = 0.f;
    if (src >= 0) {
      const float* wr = x + ((size_t)b * S_ + src) * D_;
      *(float4*)&win[j][0] = *(const float4*)&wr[d0];
      *(float4*)&win[j][4] = *(const float4*)&wr[d0 + 4];
#pragma unroll
      for (int t = 0; t < 8; ++t) part += xi[t] * win[j][t];
    } else {
#pragma unroll
      for (int t = 0; t < 8; ++t) win[j][t] = 0.f;
    }
    sc[j] = part;
  }
#pragma unroll
  for (int off = 1; off < 64; off <<= 1) {
#pragma unroll
    for (int j = 0; j < 5; ++j) sc[j] += __shfl_xor(sc[j], off, 64);
  }
  const float scale = 0.04419417382415922f;  // 1/sqrt(512)
  float m = sc[0] * scale;
#pragma unroll
  for (int j = 1; j < 5; ++j) m = fmaxf(m, sc[j] * scale);
  float w[5], lsum = 0.f;
#pragma unroll
  for (int j = 0; j < 5; ++j) { w[j] = expf(sc[j] * scale - m); lsum += w[j]; }
  const float inv = oscale / lsum;
  float o[8] = {};
#pragma unroll
  for (int j = 0; j < 5; ++j)
#pragma unroll
    for (int t = 0; t < 8; ++t) o[t] += w[j] * win[j][t];
  unsigned short* orow = out + ((size_t)b * S_ + s) * D_;
  uint4 pk;
  pk.x = pk2(o[0] * inv, o[1] * inv);
  pk.y = pk2(o[2] * inv, o[3] * inv);
  pk.z = pk2(o[4] * inv, o[5] * inv);
  pk.w = pk2(o[6] * inv, o[7] * inv);
  *(uint4*)&orow[d0] = pk;
}

// ---------------------------------------------------------------------------
// MFMA flash attention (bf16 in, f32 out). Unchanged from round 2.
// ---------------------------------------------------------------------------
__global__ __launch_bounds__(256) void attn_mfma_kernel(
    const unsigned short* __restrict__ q, const unsigned short* __restrict__ k,
    const unsigned short* __restrict__ v, float* __restrict__ x) {
  const int bid = blockIdx.x;          // 512 = b(4) * h(8) * qt(16)
  const int qt = bid & 15;
  const int h  = (bid >> 4) & 7;
  const int b  = bid >> 7;
  const int tid = threadIdx.x;
  const int wv = tid >> 6, lane = tid & 63;
  const int c = lane & 15, g = lane >> 4;

  __shared__ unsigned short Ks[64][80];   // [key][feat], padded
  __shared__ unsigned short Vt[64][80];   // [d][key], padded

  bf16x8 Qf[2][2];
  const size_t qbase = ((size_t)b * S_ + qt * 128 + wv * 32) * D_ + h * 64;
#pragma unroll
  for (int rt = 0; rt < 2; ++rt)
#pragma unroll
    for (int fs = 0; fs < 2; ++fs)
      Qf[rt][fs] = *(const bf16x8*)(q + qbase + (size_t)(rt * 16 + c) * D_ + fs * 32 + g * 8);

  f32x4 acc[2][4];
#pragma unroll
  for (int rt = 0; rt < 2; ++rt)
#pragma unroll
    for (int ds = 0; ds < 4; ++ds) acc[rt][ds] = f32x4{0.f, 0.f, 0.f, 0.f};
  float mrow[2] = {-INFINITY, -INFINITY}, lrow[2] = {0.f, 0.f};

  const int kk = tid >> 2, kf = (tid & 3) << 4;
  const int vd = tid & 63, vh = tid >> 6;

  for (int kt = 0; kt < S_ / 64; ++kt) {
    const int kb = kt * 64;
    __syncthreads();
    {
      const unsigned short* kg_ = k + ((size_t)b * S_ + kb + kk) * D_ + h * 64 + kf;
      *(uint4*)&Ks[kk][kf]     = *(const uint4*)kg_;
      *(uint4*)&Ks[kk][kf + 8] = *(const uint4*)(kg_ + 8);
    }
    {
      const unsigned short* vg_ = v + ((size_t)b * S_ + kb + vh * 16) * D_ + h * 64 + vd;
      unsigned short tmp[16];
#pragma unroll
      for (int i = 0; i < 16; ++i) tmp[i] = vg_[(size_t)i * D_];
      *(uint4*)&Vt[vd][vh * 16]     = *(uint4*)&tmp[0];
      *(uint4*)&Vt[vd][vh * 16 + 8] = *(uint4*)&tmp[8];
    }
    __syncthreads();

#pragma unroll
    for (int rt = 0; rt < 2; ++rt) {
      f32x4 sf[4];
#pragma unroll
      for (int ks = 0; ks < 4; ++ks) {
        bf16x8 ka0 = *(const bf16x8*)&Ks[ks * 16 + c][g * 8];
        bf16x8 ka1 = *(const bf16x8*)&Ks[ks * 16 + c][32 + g * 8];
        f32x4 z = f32x4{0.f, 0.f, 0.f, 0.f};
        z = __builtin_amdgcn_mfma_f32_16x16x32_bf16(ka0, Qf[rt][0], z, 0, 0, 0);
        z = __builtin_amdgcn_mfma_f32_16x16x32_bf16(ka1, Qf[rt][1], z, 0, 0, 0);
        sf[ks] = z;
      }
      float mt = sf[0][0];
#pragma unroll
      for (int st = 0; st < 4; ++st)
#pragma unroll
        for (int r = 0; r < 4; ++r) mt = fmaxf(mt, sf[st][r]);
      mt = fmaxf(mt, __shfl_xor(mt, 16, 64));
      mt = fmaxf(mt, __shfl_xor(mt, 32, 64));
      const float mnew = fmaxf(mrow[rt], mt);
      const float corr = __expf(mrow[rt] - mnew);
      float p[4][4];
      float ts = 0.f;
#pragma unroll
      for (int st = 0; st < 4; ++st)
#pragma unroll
        for (int r = 0; r < 4; ++r) { p[st][r] = __expf(sf[st][r] - mnew); ts += p[st][r]; }
      ts += __shfl_xor(ts, 16, 64);
      ts += __shfl_xor(ts, 32, 64);
      lrow[rt] = lrow[rt] * corr + ts;
      mrow[rt] = mnew;
#pragma unroll
      for (int ds = 0; ds < 4; ++ds) {
        acc[rt][ds][0] *= corr; acc[rt][ds][1] *= corr;
        acc[rt][ds][2] *= corr; acc[rt][ds][3] *= corr;
      }
#pragma unroll
      for (int pr = 0; pr < 2; ++pr) {
        unsigned w00 = pk2(p[2 * pr][0], p[2 * pr][1]);
        unsigned w01 = pk2(p[2 * pr][2], p[2 * pr][3]);
        unsigned w10 = pk2(p[2 * pr + 1][0], p[2 * pr + 1][1]);
        unsigned w11 = pk2(p[2 * pr + 1][2], p[2 * pr + 1][3]);
        unsigned n00 = __shfl_xor(w00, 16, 64), n01 = __shfl_xor(w01, 16, 64);
        unsigned n10 = __shfl_xor(w10, 16, 64), n11 = __shfl_xor(w11, 16, 64);
        const bool odd = (g & 1);
        unsigned pe00 = odd ? n00 : w00, pe01 = odd ? n01 : w01;
        unsigned pe10 = odd ? n10 : w10, pe11 = odd ? n11 : w11;
        unsigned po00 = odd ? w00 : n00, po01 = odd ? w01 : n01;
        unsigned po10 = odd ? w10 : n10, po11 = odd ? w11 : n11;
        unsigned qe00 = __shfl_xor(pe00, 32, 64), qe01 = __shfl_xor(pe01, 32, 64);
        unsigned qe10 = __shfl_xor(pe10, 32, 64), qe11 = __shfl_xor(pe11, 32, 64);
        unsigned qo00 = __shfl_xor(po00, 32, 64), qo01 = __shfl_xor(po01, 32, 64);
        unsigned qo10 = __shfl_xor(po10, 32, 64), qo11 = __shfl_xor(po11, 32, 64);
        const bool need = (g == 1) || (g == 2);
        unsigned re00 = need ? qe00 : pe00, re01 = need ? qe01 : pe01;
        unsigned re10 = need ? qe10 : pe10, re11 = need ? qe11 : pe11;
        unsigned ro00 = need ? qo00 : po00, ro01 = need ? qo01 : po01;
        unsigned ro10 = need ? qo10 : po10, ro11 = need ? qo11 : po11;
        const bool hi = (g >> 1);
        union { unsigned u[4]; bf16x8 v; } pb;
        pb.u[0] = hi ? re10 : re00;
        pb.u[1] = hi ? re11 : re01;
        pb.u[2] = hi ? ro10 : ro00;
        pb.u[3] = hi ? ro11 : ro01;
#pragma unroll
        for (int ds = 0; ds < 4; ++ds) {
          bf16x8 va = *(const bf16x8*)&Vt[ds * 16 + c][pr * 32 + g * 8];
          acc[rt][ds] = __builtin_amdgcn_mfma_f32_16x16x32_bf16(va, pb.v, acc[rt][ds], 0, 0, 0);
        }
      }
    }
  }
#pragma unroll
  for (int rt = 0; rt < 2; ++rt) {
    const float inv = 1.f / lrow[rt];
    float* xrow = x + ((size_t)b * S_ + qt * 128 + wv * 32 + rt * 16 + c) * D_ + h * 64;
#pragma unroll
    for (int ds = 0; ds < 4; ++ds)
#pragma unroll
      for (int r = 0; r < 4; ++r)
        xrow[ds * 16 + 4 * g + r] = acc[rt][ds][r] * inv;
  }
}

// ---------------------------------------------------------------------------
extern "C" void kernel_launch(void* const* d_in, const int* in_sizes, int n_in,
                              void* d_out, int out_size, void* d_ws, size_t ws_size,
                              hipStream_t stream) {
  const float* query = (const float*)d_in[0];
  const float* key   = (const float*)d_in[1];
  const float* value = (const float*)d_in[2];
  const float* W_fk = (const float*)d_in[4];
  const float* b_fk = (const float*)d_in[5];
  const float* W0   = (const float*)d_in[6];
  const float* b0   = (const float*)d_in[7];
  const float* Wout = (const float*)d_in[8];
  const float* bout = (const float*)d_in[9];
  float* out = (float*)d_out;

  char* ws = (char*)d_ws;
  float* kfk_f32   = (float*)ws;                       // 16MB @ 0 (later q_bf16)
  float* x_f32     = (float*)(ws + (16u << 20));       // 16MB @ 16MB
  unsigned short* k_bf16 = (unsigned short*)(ws + (32u << 20));  // 8MB @ 32MB
  unsigned short* v_bf16 = (unsigned short*)(ws + (40u << 20));  // 8MB @ 40MB
  unsigned short* q_bf16 = (unsigned short*)ws;        // overlays kfk after use

  dim3 mgrid(D_ / 64, BS_ / 128);   // (bn, bm): consecutive blocks share A-tile
  dim3 pgrid(BS_ * 64 / 256);
  const float qscale = 0.125f;  // 1/sqrt(dk): folded into pooled q

  // kfk = key @ W_fk + b_fk  (split-precision: feeds attention scores)
  gemm_mfma_kernel<1, 0><<<mgrid, 256, 0, stream>>>(key, W_fk, b_fk, kfk_f32);
  // k = pool(kfk) -> bf16
  local_pool_kernel<<<pgrid, 256, 0, stream>>>(kfk_f32, k_bf16, 1.0f);
  // v = value @ W0 + b0 -> bf16 (plain bf16: error averages out in PV)
  gemm_mfma_kernel<0, 1><<<mgrid, 256, 0, stream>>>(value, W0, b0, v_bf16);
  // q = pool(query) * 0.125 -> bf16 (overwrites kfk region)
  local_pool_kernel<<<pgrid, 256, 0, stream>>>(query, q_bf16, qscale);
  // x = attention(q, k, v) -> f32
  attn_mfma_kernel<<<dim3(B_ * H_ * (S_ / 128)), 256, 0, stream>>>(q_bf16, k_bf16, v_bf16, x_f32);
  // out = x @ Wout + bout  (split-precision: direct output)
  gemm_mfma_kernel<1, 0><<<mgrid, 256, 0, stream>>>(x_f32, Wout, bout, out);
}

// Round 4
// 203.154 us; speedup vs baseline: 7.5699x; 1.0755x over previous
//
#include <hip/hip_runtime.h>
#include <hip/hip_bf16.h>
#include <math.h>

#define B_  4
#define S_  2048
#define D_  512
#define H_  8
#define DK_ 64
#define BS_ (B_*S_)

using bf16x8 = __attribute__((ext_vector_type(8))) short;
using f32x4  = __attribute__((ext_vector_type(4))) float;
using f32x16 = __attribute__((ext_vector_type(16))) float;

static __device__ inline unsigned short f2bf(float a) {
  union { __hip_bfloat16 h; unsigned short u; } x;
  x.h = __float2bfloat16(a); return x.u;
}
static __device__ inline float bf16f(unsigned short u) {
  union { unsigned u32; float f; } x; x.u32 = (unsigned)u << 16; return x.f;
}
static __device__ inline unsigned pk2(float a, float b) {
  return (unsigned)f2bf(a) | ((unsigned)f2bf(b) << 16);
}

// ---------------------------------------------------------------------------
// MFMA GEMM (unchanged from round 3): C = A @ W + bias, bf16 split-precision.
// ---------------------------------------------------------------------------
template <int SPLIT, int BF16OUT>
__global__ __launch_bounds__(256) void gemm_mfma_kernel(
    const float* __restrict__ A, const float* __restrict__ W,
    const float* __restrict__ bias, void* __restrict__ Cv) {
  const int bn = blockIdx.x;      // 8
  const int bm = blockIdx.y;      // 64
  const int tid = threadIdx.x;
  const int wv = tid >> 6, lane = tid & 63;
  const int c = lane & 15, g = lane >> 4;

  __shared__ unsigned short As[SPLIT + 1][128][72];
  __shared__ unsigned short Wt[SPLIT + 1][64][72];

  f32x4 acc[2][4];
#pragma unroll
  for (int rt = 0; rt < 2; ++rt)
#pragma unroll
    for (int ds = 0; ds < 4; ++ds) acc[rt][ds] = f32x4{0.f, 0.f, 0.f, 0.f};

  const int arow = tid >> 1, ah = (tid & 1) * 32;
  const int wn = tid & 63, wkg = (tid >> 6) * 16;

  for (int k0 = 0; k0 < D_; k0 += 64) {
    float af[32];
    const float* ag = A + ((size_t)(bm * 128 + arow)) * D_ + k0 + ah;
#pragma unroll
    for (int i = 0; i < 8; ++i) *(float4*)&af[i * 4] = *(const float4*)(ag + i * 4);
    float wf[16];
    const float* wg = W + (size_t)(k0 + wkg) * D_ + bn * 64 + wn;
#pragma unroll
    for (int i = 0; i < 16; ++i) wf[i] = wg[(size_t)i * D_];

    __syncthreads();
#pragma unroll
    for (int grp = 0; grp < 4; ++grp) {
      unsigned h[4], l[4];
#pragma unroll
      for (int p = 0; p < 4; ++p) {
        float f0 = af[grp * 8 + p * 2], f1 = af[grp * 8 + p * 2 + 1];
        unsigned short h0 = f2bf(f0), h1 = f2bf(f1);
        h[p] = (unsigned)h0 | ((unsigned)h1 << 16);
        if constexpr (SPLIT) l[p] = pk2(f0 - bf16f(h0), f1 - bf16f(h1));
      }
      uint4 uh; uh.x = h[0]; uh.y = h[1]; uh.z = h[2]; uh.w = h[3];
      *(uint4*)&As[0][arow][ah + grp * 8] = uh;
      if constexpr (SPLIT) {
        uint4 ul; ul.x = l[0]; ul.y = l[1]; ul.z = l[2]; ul.w = l[3];
        *(uint4*)&As[1][arow][ah + grp * 8] = ul;
      }
    }
#pragma unroll
    for (int grp = 0; grp < 2; ++grp) {
      unsigned h[4], l[4];
#pragma unroll
      for (int p = 0; p < 4; ++p) {
        float f0 = wf[grp * 8 + p * 2], f1 = wf[grp * 8 + p * 2 + 1];
        unsigned short h0 = f2bf(f0), h1 = f2bf(f1);
        h[p] = (unsigned)h0 | ((unsigned)h1 << 16);
        if constexpr (SPLIT) l[p] = pk2(f0 - bf16f(h0), f1 - bf16f(h1));
      }
      uint4 uh; uh.x = h[0]; uh.y = h[1]; uh.z = h[2]; uh.w = h[3];
      *(uint4*)&Wt[0][wn][wkg + grp * 8] = uh;
      if constexpr (SPLIT) {
        uint4 ul; ul.x = l[0]; ul.y = l[1]; ul.z = l[2]; ul.w = l[3];
        *(uint4*)&Wt[1][wn][wkg + grp * 8] = ul;
      }
    }
    __syncthreads();

#pragma unroll
    for (int ksub = 0; ksub < 2; ++ksub) {
      bf16x8 bh[2], bl[2];
#pragma unroll
      for (int rt = 0; rt < 2; ++rt) {
        bh[rt] = *(const bf16x8*)&As[0][wv * 32 + rt * 16 + c][ksub * 32 + g * 8];
        if constexpr (SPLIT)
          bl[rt] = *(const bf16x8*)&As[1][wv * 32 + rt * 16 + c][ksub * 32 + g * 8];
      }
#pragma unroll
      for (int ds = 0; ds < 4; ++ds) {
        bf16x8 ah_ = *(const bf16x8*)&Wt[0][ds * 16 + c][ksub * 32 + g * 8];
#pragma unroll
        for (int rt = 0; rt < 2; ++rt)
          acc[rt][ds] = __builtin_amdgcn_mfma_f32_16x16x32_bf16(ah_, bh[rt], acc[rt][ds], 0, 0, 0);
        if constexpr (SPLIT) {
          bf16x8 al_ = *(const bf16x8*)&Wt[1][ds * 16 + c][ksub * 32 + g * 8];
#pragma unroll
          for (int rt = 0; rt < 2; ++rt) {
            acc[rt][ds] = __builtin_amdgcn_mfma_f32_16x16x32_bf16(ah_, bl[rt], acc[rt][ds], 0, 0, 0);
            acc[rt][ds] = __builtin_amdgcn_mfma_f32_16x16x32_bf16(al_, bh[rt], acc[rt][ds], 0, 0, 0);
          }
        }
      }
    }
  }

#pragma unroll
  for (int rt = 0; rt < 2; ++rt) {
    const size_t m = (size_t)bm * 128 + wv * 32 + rt * 16 + c;
#pragma unroll
    for (int ds = 0; ds < 4; ++ds) {
      const int n = bn * 64 + ds * 16 + 4 * g;
      float4 bv = *(const float4*)&bias[n];
      float o0 = acc[rt][ds][0] + bv.x, o1 = acc[rt][ds][1] + bv.y;
      float o2 = acc[rt][ds][2] + bv.z, o3 = acc[rt][ds][3] + bv.w;
      if constexpr (BF16OUT) {
        uint2 p; p.x = pk2(o0, o1); p.y = pk2(o2, o3);
        *(uint2*)((unsigned short*)Cv + m * D_ + n) = p;
      } else {
        float4 o; o.x = o0; o.y = o1; o.z = o2; o.w = o3;
        *(float4*)((float*)Cv + m * D_ + n) = o;
      }
    }
  }
}

// ---------------------------------------------------------------------------
// Causal local-window (L=5) softmax pooling; f32 in, bf16 out (scaled).
// ---------------------------------------------------------------------------
__global__ __launch_bounds__(256) void local_pool_kernel(
    const float* __restrict__ x, unsigned short* __restrict__ out,
    float oscale) {
  const int gtid = blockIdx.x * 256 + threadIdx.x;
  const int wave = gtid >> 6;
  const int lane = gtid & 63;
  if (wave >= BS_) return;
  const int b = wave / S_, s = wave % S_;
  const float* xrow = x + ((size_t)b * S_ + s) * D_;
  const int d0 = lane * 8;
  float xi[8];
  *(float4*)&xi[0] = *(const float4*)&xrow[d0];
  *(float4*)&xi[4] = *(const float4*)&xrow[d0 + 4];
  float win[5][8];
  float sc[5];
#pragma unroll
  for (int j = 0; j < 5; ++j) {
    int src = s - 4 + j;
    float part = 0.f;
    if (src >= 0) {
      const float* wr = x + ((size_t)b * S_ + src) * D_;
      *(float4*)&win[j][0] = *(const float4*)&wr[d0];
      *(float4*)&win[j][4] = *(const float4*)&wr[d0 + 4];
#pragma unroll
      for (int t = 0; t < 8; ++t) part += xi[t] * win[j][t];
    } else {
#pragma unroll
      for (int t = 0; t < 8; ++t) win[j][t] = 0.f;
    }
    sc[j] = part;
  }
#pragma unroll
  for (int off = 1; off < 64; off <<= 1) {
#pragma unroll
    for (int j = 0; j < 5; ++j) sc[j] += __shfl_xor(sc[j], off, 64);
  }
  const float scale = 0.04419417382415922f;  // 1/sqrt(512)
  float m = sc[0] * scale;
#pragma unroll
  for (int j = 1; j < 5; ++j) m = fmaxf(m, sc[j] * scale);
  float w[5], lsum = 0.f;
#pragma unroll
  for (int j = 0; j < 5; ++j) { w[j] = expf(sc[j] * scale - m); lsum += w[j]; }
  const float inv = oscale / lsum;
  float o[8] = {};
#pragma unroll
  for (int j = 0; j < 5; ++j)
#pragma unroll
    for (int t = 0; t < 8; ++t) o[t] += w[j] * win[j][t];
  unsigned short* orow = out + ((size_t)b * S_ + s) * D_;
  uint4 pk;
  pk.x = pk2(o[0] * inv, o[1] * inv);
  pk.y = pk2(o[2] * inv, o[3] * inv);
  pk.z = pk2(o[4] * inv, o[5] * inv);
  pk.w = pk2(o[6] * inv, o[7] * inv);
  *(uint4*)&orow[d0] = pk;
}

// ---------------------------------------------------------------------------
// 32x32x16 MFMA flash attention. 4 warps x 32 q-rows = 128 q/block.
// Swapped QK^T: S^T = mfma(K, Q): col = q = lane&31, row = key =
// (reg&3)+8*(reg>>2)+4*(lane>>5) (+32 per subtile). q is pre-scaled by
// 0.125*log2(e) so softmax runs in exp2 domain (v_exp_f32 native).
// P^T -> PV B-operand via v_permlane32_swap_b32: for B-frag covering keys
// 16kc..16kc+15, lane hi needs words [W(4kc..4kc+1) from hi'=0,
// W(4kc+2..4kc+3) from hi'=1] -- swap(W0,W2) makes W0' = [W0_lo|W2_lo] (word0
// for both halves) and W2' = [W0_hi|W2_hi] (word2 for both halves); ditto
// (W1,W3) -> words 1,3. Zero cndmasks.
// K and V^T LDS tiles [64][64] with byte-XOR ((row&7)<<4): every b128
// read/write lands at the 8-dword/bank minimum (conflict-free throughput).
// ---------------------------------------------------------------------------
__global__ __launch_bounds__(256) void attn_mfma32_kernel(
    const unsigned short* __restrict__ q, const unsigned short* __restrict__ k,
    const unsigned short* __restrict__ v, float* __restrict__ x) {
  const int bid = blockIdx.x;          // 512 = b(4) * h(8) * qt(16)
  const int qt = bid & 15;
  const int h  = (bid >> 4) & 7;
  const int b  = bid >> 7;
  const int tid = threadIdx.x;
  const int w = tid >> 6, l = tid & 63;
  const int ql = l & 31, hi = l >> 5;

  __shared__ __align__(16) unsigned short Ks[64 * 64];
  __shared__ __align__(16) unsigned short Vt[64 * 64];
  char* KsB = (char*)Ks;
  char* VtB = (char*)Vt;

  // Q fragments (B-operand): Qf[f][j] = q[qrow][16f + 8hi + j]
  bf16x8 Qf[4];
  const unsigned short* qg =
      q + ((size_t)b * S_ + qt * 128 + w * 32 + ql) * D_ + h * 64 + hi * 8;
#pragma unroll
  for (int f = 0; f < 4; ++f) Qf[f] = *(const bf16x8*)(qg + f * 16);

  f32x16 accO[2] = {};           // O^T: [d-tile 32][q]; zero-init
  float m = -INFINITY, lsum = 0.f;

  // staging: K rows coalesced; V columns (transpose via 16 coalesced 2B rows)
  const int krow = tid >> 2, kcp = tid & 3;
  const int vd = tid & 63, vhalf = tid >> 6;
  const unsigned short* kg0 = k + ((size_t)b * S_ + krow) * D_ + h * 64 + kcp * 16;
  const unsigned short* vg0 = v + ((size_t)b * S_ + vhalf * 16) * D_ + h * 64 + vd;
  const int ka0 = (krow * 128 + kcp * 32) ^ ((krow & 7) << 4);
  const int ka1 = (krow * 128 + kcp * 32 + 16) ^ ((krow & 7) << 4);
  const int va0 = (vd * 128 + vhalf * 32) ^ ((vd & 7) << 4);
  const int va1 = (vd * 128 + vhalf * 32 + 16) ^ ((vd & 7) << 4);

  // prefetch tile 0 into registers
  uint4 rk0 = *(const uint4*)(kg0);
  uint4 rk1 = *(const uint4*)(kg0 + 8);
  unsigned short rv[16];
#pragma unroll
  for (int i = 0; i < 16; ++i) rv[i] = vg0[(size_t)i * D_];

  for (int kt = 0; kt < S_ / 64; ++kt) {
    __syncthreads();                      // prev compute done reading LDS
    *(uint4*)(KsB + ka0) = rk0;
    *(uint4*)(KsB + ka1) = rk1;
    *(uint4*)(VtB + va0) = *(uint4*)&rv[0];
    *(uint4*)(VtB + va1) = *(uint4*)&rv[8];
    __syncthreads();
    if (kt + 1 < S_ / 64) {               // prefetch next tile (hides HBM/L2)
      const size_t koff = (size_t)(kt + 1) * 64 * D_;
      rk0 = *(const uint4*)(kg0 + koff);
      rk1 = *(const uint4*)(kg0 + koff + 8);
#pragma unroll
      for (int i = 0; i < 16; ++i) rv[i] = vg0[koff + (size_t)i * D_];
    }

    // ---- QK^T: two 32-key subtiles ----
    f32x16 sA = {}, sB = {};
    __builtin_amdgcn_s_setprio(1);
#pragma unroll
    for (int f = 0; f < 4; ++f) {
      bf16x8 a0 = *(const bf16x8*)(KsB + ((ql * 128 + f * 32 + hi * 16) ^ ((ql & 7) << 4)));
      bf16x8 a1 = *(const bf16x8*)(KsB + (((ql + 32) * 128 + f * 32 + hi * 16) ^ ((ql & 7) << 4)));
      sA = __builtin_amdgcn_mfma_f32_32x32x16_bf16(a0, Qf[f], sA, 0, 0, 0);
      sB = __builtin_amdgcn_mfma_f32_32x32x16_bf16(a1, Qf[f], sB, 0, 0, 0);
    }
    __builtin_amdgcn_s_setprio(0);

    // ---- online softmax (exp2 domain), defer-max THR=10 ----
    float mt = fmaxf(sA[0], sB[0]);
#pragma unroll
    for (int r = 1; r < 16; ++r) mt = fmaxf(mt, fmaxf(sA[r], sB[r]));
    mt = fmaxf(mt, __shfl_xor(mt, 32, 64));
    if (!__all(mt <= m + 10.0f)) {
      const float mn = fmaxf(m, mt);
      const float corr = exp2f(m - mn);
      m = mn;
      lsum *= corr;
#pragma unroll
      for (int dt = 0; dt < 2; ++dt)
#pragma unroll
        for (int r = 0; r < 16; ++r) accO[dt][r] *= corr;
    }
    float pA[16], pB[16];
    float ts = 0.f;
#pragma unroll
    for (int r = 0; r < 16; ++r) { pA[r] = exp2f(sA[r] - m); ts += pA[r]; }
#pragma unroll
    for (int r = 0; r < 16; ++r) { pB[r] = exp2f(sB[r] - m); ts += pB[r]; }
    lsum += ts;

    // ---- pack P -> bf16 words; W[2t]=keys(8t+4hi+{0,1}), W[2t+1]={2,3} ----
    unsigned WA[8], WB[8];
#pragma unroll
    for (int t = 0; t < 4; ++t) {
      WA[2 * t]     = pk2(pA[4 * t], pA[4 * t + 1]);
      WA[2 * t + 1] = pk2(pA[4 * t + 2], pA[4 * t + 3]);
      WB[2 * t]     = pk2(pB[4 * t], pB[4 * t + 1]);
      WB[2 * t + 1] = pk2(pB[4 * t + 2], pB[4 * t + 3]);
    }

    // ---- PV: 4 key-chunks x 2 d-tiles ----
#pragma unroll
    for (int kc = 0; kc < 4; ++kc) {
      unsigned w0 = (kc < 2) ? WA[(kc & 1) * 4 + 0] : WB[(kc & 1) * 4 + 0];
      unsigned w1 = (kc < 2) ? WA[(kc & 1) * 4 + 1] : WB[(kc & 1) * 4 + 1];
      unsigned w2 = (kc < 2) ? WA[(kc & 1) * 4 + 2] : WB[(kc & 1) * 4 + 2];
      unsigned w3 = (kc < 2) ? WA[(kc & 1) * 4 + 3] : WB[(kc & 1) * 4 + 3];
      asm volatile("v_permlane32_swap_b32 %0, %1" : "+v"(w0), "+v"(w2));
      asm volatile("v_permlane32_swap_b32 %0, %1" : "+v"(w1), "+v"(w3));
      union { unsigned u[4]; bf16x8 v8; } pb;
      pb.u[0] = w0; pb.u[1] = w1; pb.u[2] = w2; pb.u[3] = w3;
      __builtin_amdgcn_s_setprio(1);
#pragma unroll
      for (int dt = 0; dt < 2; ++dt) {
        const int vrow = dt * 32 + ql;
        bf16x8 va = *(const bf16x8*)(VtB + ((vrow * 128 + kc * 32 + hi * 16) ^ ((ql & 7) << 4)));
        accO[dt] = __builtin_amdgcn_mfma_f32_32x32x16_bf16(va, pb.v8, accO[dt], 0, 0, 0);
      }
      __builtin_amdgcn_s_setprio(0);
    }
  }

  // ---- epilogue: O[q][d] = accO/ltot; d = 32dt + 4hi + 8g0 + j ----
  float ltot = lsum + __shfl_xor(lsum, 32, 64);
  const float inv = 1.f / ltot;
  float* xrow = x + ((size_t)b * S_ + qt * 128 + w * 32 + ql) * D_ + h * 64;
#pragma unroll
  for (int dt = 0; dt < 2; ++dt)
#pragma unroll
    for (int g0 = 0; g0 < 4; ++g0) {
      float4 o;
      o.x = accO[dt][4 * g0 + 0] * inv;
      o.y = accO[dt][4 * g0 + 1] * inv;
      o.z = accO[dt][4 * g0 + 2] * inv;
      o.w = accO[dt][4 * g0 + 3] * inv;
      *(float4*)&xrow[dt * 32 + hi * 4 + g0 * 8] = o;
    }
}

// ---------------------------------------------------------------------------
extern "C" void kernel_launch(void* const* d_in, const int* in_sizes, int n_in,
                              void* d_out, int out_size, void* d_ws, size_t ws_size,
                              hipStream_t stream) {
  const float* query = (const float*)d_in[0];
  const float* key   = (const float*)d_in[1];
  const float* value = (const float*)d_in[2];
  const float* W_fk = (const float*)d_in[4];
  const float* b_fk = (const float*)d_in[5];
  const float* W0   = (const float*)d_in[6];
  const float* b0   = (const float*)d_in[7];
  const float* Wout = (const float*)d_in[8];
  const float* bout = (const float*)d_in[9];
  float* out = (float*)d_out;

  char* ws = (char*)d_ws;
  float* kfk_f32   = (float*)ws;                       // 16MB @ 0 (later q_bf16)
  float* x_f32     = (float*)(ws + (16u << 20));       // 16MB @ 16MB
  unsigned short* k_bf16 = (unsigned short*)(ws + (32u << 20));  // 8MB @ 32MB
  unsigned short* v_bf16 = (unsigned short*)(ws + (40u << 20));  // 8MB @ 40MB
  unsigned short* q_bf16 = (unsigned short*)ws;        // overlays kfk after use

  dim3 mgrid(D_ / 64, BS_ / 128);
  dim3 pgrid(BS_ * 64 / 256);
  // 1/sqrt(dk) * log2(e): softmax runs in exp2 domain
  const float qscale = 0.125f * 1.4426950408889634f;

  gemm_mfma_kernel<1, 0><<<mgrid, 256, 0, stream>>>(key, W_fk, b_fk, kfk_f32);
  local_pool_kernel<<<pgrid, 256, 0, stream>>>(kfk_f32, k_bf16, 1.0f);
  gemm_mfma_kernel<0, 1><<<mgrid, 256, 0, stream>>>(value, W0, b0, v_bf16);
  local_pool_kernel<<<pgrid, 256, 0, stream>>>(query, q_bf16, qscale);
  attn_mfma32_kernel<<<dim3(B_ * H_ * (S_ / 128)), 256, 0, stream>>>(q_bf16, k_bf16, v_bf16, x_f32);
  gemm_mfma_kernel<1, 0><<<mgrid, 256, 0, stream>>>(x_f32, Wout, bout, out);
}